// Round 18
// baseline (55.467 us; speedup 1.0000x reference)
//
#include <hip/hip_runtime.h>
#include <hip/hip_bf16.h>

// B=16, C=64, P=128, L=16, D=256, NPF=256, NRFF=128, FEAT=656
// ws layout (float slots):
#define WS_WK0   0        // 16     wk0 = Wk0^T q0
#define WS_A     16       // 256    A = Wq1^T Wk1
#define WS_E0    272      // 4096   E0 = Pp0 * Wv0  (256 x 16), f32 (for c0)
#define WS_BT    4368     // 20480 f32-slots = 40960 ushort: BTall[256][160] bf16
//   BTall[d][kk]: 0..15 Px; 16..31 E1; 32..95 Psin; 96..159 Pcos

typedef float f32x4 __attribute__((ext_vector_type(4)));
typedef short s16x8 __attribute__((ext_vector_type(8)));
typedef short s16x4 __attribute__((ext_vector_type(4)));

static __device__ __forceinline__ short bf16b(float f) {
  __hip_bfloat16 h = __float2bfloat16(f);
  return __builtin_bit_cast(short, h);
}
static __device__ __forceinline__ float bf2f(short s) {
  unsigned u = ((unsigned)(unsigned short)s) << 16;
  return __builtin_bit_cast(float, u);
}

// lgkmcnt-only barrier: orders LDS producer->consumer without draining vmcnt.
static __device__ __forceinline__ void bar_lds() {
  asm volatile("s_waitcnt lgkmcnt(0)\n\ts_barrier" ::: "memory");
}

__global__ __launch_bounds__(512)
void pre_kernel(const float* __restrict__ Wq, const float* __restrict__ Wk,
                const float* __restrict__ Wv, const float* __restrict__ pw,
                float* __restrict__ ws)
{
  __shared__ float lds[8704];
  const int t = threadIdx.x;
  const int blk = blockIdx.x;
  ushort* bt = (ushort*)(ws + WS_BT);

  if (blk == 0) {
    {
      const int d = t >> 1;
      const int lb = (t & 1) * 8;
      #pragma unroll
      for (int h = 0; h < 2; ++h) {
        const float4 vq = *(const float4*)(Wq + 4096 + t*8 + h*4);
        lds[(lb+h*4+0)*256 + d] = vq.x;
        lds[(lb+h*4+1)*256 + d] = vq.y;
        lds[(lb+h*4+2)*256 + d] = vq.z;
        lds[(lb+h*4+3)*256 + d] = vq.w;
        const float4 vk = *(const float4*)(Wk + 4096 + t*8 + h*4);
        lds[4096 + (lb+h*4+0)*256 + d] = vk.x;
        lds[4096 + (lb+h*4+1)*256 + d] = vk.y;
        lds[4096 + (lb+h*4+2)*256 + d] = vk.z;
        lds[4096 + (lb+h*4+3)*256 + d] = vk.w;
      }
    }
    if (t < 256) {
      float s = 0.f;
      #pragma unroll
      for (int q = 0; q < 4; ++q) {
        const float4 v = *(const float4*)(Wq + t*16 + q*4);
        s += v.x + v.y + v.z + v.w;           // q0[d]
      }
      lds[8192 + t] = s;
    }
    __syncthreads();
    if (t < 256) {
      const int l1 = t >> 4, l2 = t & 15;
      const float* r1 = lds + l1*256;
      const float* r2 = lds + 4096 + l2*256;
      float s = 0.f;
      #pragma unroll 8
      for (int dq = 0; dq < 64; ++dq) {
        const float4 a = *(const float4*)(r1 + dq*4);
        const float4 b = *(const float4*)(r2 + dq*4);
        s += a.x*b.x + a.y*b.y + a.z*b.z + a.w*b.w;    // A[l1,l2]
      }
      ws[WS_A + t] = s;
    }
    if (t < 256) {                 // wk0 partial sums
      const int l = t & 15, ch = t >> 4;
      float s = 0.f;
      #pragma unroll
      for (int i = 0; i < 16; ++i)
        s += lds[8192 + ch*16 + i] * Wk[(ch*16 + i)*16 + l];
      lds[8448 + t] = s;
    }
    __syncthreads();
    if (t < 16) {
      float s = 0.f;
      #pragma unroll
      for (int ch = 0; ch < 16; ++ch) s += lds[8448 + ch*16 + t];
      ws[WS_WK0 + t] = s;          // wk0[l]
    }
  } else if (blk <= 16) {
    const int deg = (blk <= 8) ? 0 : 1;
    {
      const int f = t >> 1;
      const int lb = (t & 1) * 8;
      #pragma unroll
      for (int h = 0; h < 2; ++h) {
        const float4 v = *(const float4*)(Wv + deg*4096 + t*8 + h*4);
        lds[(lb+h*4+0)*256 + f] = v.x;
        lds[(lb+h*4+1)*256 + f] = v.y;
        lds[(lb+h*4+2)*256 + f] = v.z;
        lds[(lb+h*4+3)*256 + f] = v.w;
      }
    }
    __syncthreads();
    const int d = ((blk-1) & 7)*32 + (t >> 4);
    const int l = t & 15;
    const float* pr = pw + d*656 + (deg ? 272 : 16);
    const float* wv = lds + l*256;
    float s = 0.f;
    #pragma unroll 8
    for (int fq = 0; fq < 64; ++fq) {
      const float4 a = *(const float4*)(pr + fq*4);
      const float4 b = *(const float4*)(wv + fq*4);
      s += a.x*b.x + a.y*b.y + a.z*b.z + a.w*b.w;
    }
    if (deg == 0) {
      ws[WS_E0 + d*16 + l] = s;
      bt[d*160 + l] = (ushort)bf16b(pw[d*656 + l]);
    } else {
      bt[d*160 + 16 + l] = (ushort)bf16b(s);
    }
  } else {
    #pragma unroll 4
    for (int k = 0; k < 64; ++k) {
      const int d = k*4 + (t >> 7);
      const int j = t & 127;
      const float v = (j < 64) ? pw[d*656 + 528 + j] : pw[d*656 + 592 + (j-64)];
      bt[d*160 + 32 + j] = (ushort)bf16b(v);
    }
  }
}

__global__ __launch_bounds__(256, 2)
void main_kernel(const float* __restrict__ x, const float* __restrict__ fw,
                 const float* __restrict__ fb, const float* __restrict__ pb,
                 const float* __restrict__ ws, float* __restrict__ out)
{
  __shared__ short Xb[64*40];    // bf16 X [c][k], 80B rows; k in [16,32) zero
  __shared__ short XbT[16*72];   // bf16 X^T [l][c], 144B rows
  __shared__ short Fwt[64*40];   // bf16 fw^T [j][k]; k>=16 zero
  __shared__ float fbs[64];
  __shared__ float Gs[256];      // G = X^T X (f32, from MFMA)
  __shared__ float AGs[256];     // AG = A * G
  __shared__ float tls[16];      // G * wk0
  __shared__ float c0s[256];     // pb + E0 * tls
  __shared__ short Abf[20*64*8]; // bf16 acts [kt][c][8]: kt0-1=x, kt2-3=M, kt4-11=sin, kt12-19=cos
  // ~36.6 KB

  const int t = threadIdx.x;
  const int b = blockIdx.x >> 7;
  const int p = blockIdx.x & 127;

  const int lane = t & 63, w = t >> 6;
  const int n0 = w << 6;                    // wave's d-offset
  const int lr = lane & 15, lq = lane >> 4;
  const int xc = t >> 2, xl0 = (t & 3) * 4;
  const ushort* BTW = (const ushort*)(ws + WS_BT);

  // ---- P1: stage X (3 bf16 layouts) + fw^T + fb ----
  {
    const float4 v = *(const float4*)(x + (((b*64 + xc)*128 + p) << 4) + xl0);
    s16x4 xb;
    xb[0] = bf16b(v.x); xb[1] = bf16b(v.y); xb[2] = bf16b(v.z); xb[3] = bf16b(v.w);
    s16x4 z; z[0] = 0; z[1] = 0; z[2] = 0; z[3] = 0;
    *(s16x4*)&Xb[xc*40 + xl0] = xb;
    *(s16x4*)&Xb[xc*40 + 16 + xl0] = z;            // zero-pad k 16..31
    XbT[(xl0+0)*72 + xc] = xb[0];
    XbT[(xl0+1)*72 + xc] = xb[1];
    XbT[(xl0+2)*72 + xc] = xb[2];
    XbT[(xl0+3)*72 + xc] = xb[3];
    *(s16x4*)&Abf[(((xl0>>3)*64 + xc) << 3) + (xl0 & 4)] = xb;
    // fw^T: thread covers fw row l = t>>4, cols j0..j0+3
    const int l = t >> 4, j0 = (t & 15) * 4;
    const float4 f = *(const float4*)(fw + l*64 + j0);
    Fwt[(j0+0)*40 + l] = (short)bf16b(f.x);
    Fwt[(j0+1)*40 + l] = (short)bf16b(f.y);
    Fwt[(j0+2)*40 + l] = (short)bf16b(f.z);
    Fwt[(j0+3)*40 + l] = (short)bf16b(f.w);
    *(s16x4*)&Fwt[(t>>2)*40 + 16 + (t & 3)*4] = z; // zero-pad k 16..31
    if (t < 16) *(float4*)(fbs + t*4) = *(const float4*)(fb + t*4);
  }
  bar_lds();  // B1

  // ---- P2a (wave 0): G = X^T X via MFMA, A = B = XbT fragment ----
  if (w == 0) {
    f32x4 g = {};
    #pragma unroll
    for (int ks = 0; ks < 2; ++ks) {
      const s16x8 xa = *(const s16x8*)&XbT[lr*72 + ks*32 + lq*8];
      g = __builtin_amdgcn_mfma_f32_16x16x32_bf16(xa, xa, g, 0, 0, 0);
    }
    #pragma unroll
    for (int r = 0; r < 4; ++r) Gs[(lq*4 + r)*16 + lr] = g[r];
  }
  // ---- P2b (all waves): wx = X*fw via MFMA; j-block = w; sincos -> Abf ----
  {
    s16x8 xa[4];
    #pragma unroll
    for (int mi = 0; mi < 4; ++mi)
      xa[mi] = *(const s16x8*)&Xb[(mi*16 + lr)*40 + lq*8];
    const s16x8 fwf = *(const s16x8*)&Fwt[(w*16 + lr)*40 + lq*8];
    f32x4 wa[4];
    #pragma unroll
    for (int mi = 0; mi < 4; ++mi) {
      f32x4 zz = {};
      wa[mi] = __builtin_amdgcn_mfma_f32_16x16x32_bf16(xa[mi], fwf, zz, 0, 0, 0);
    }
    const float fbj = fbs[w*16 + lr];          // lane's j = w*16 + lr
    const int ktS = 4 + 2*w + (lr >> 3);       // sin row: 4 + j/8
    const int ktC = ktS + 8;                   // cos row
    const int e = lr & 7;                      // j % 8
    #pragma unroll
    for (int mi = 0; mi < 4; ++mi) {
      #pragma unroll
      for (int r = 0; r < 4; ++r) {
        const int c = mi*16 + lq*4 + r;        // D row = c
        float sv, cv;
        __sincosf(wa[mi][r] + fbj, &sv, &cv);
        Abf[(ktS*64 + c)*8 + e] = bf16b(sv);
        Abf[(ktC*64 + c)*8 + e] = bf16b(cv);
      }
    }
  }
  bar_lds();  // B2

  // ---- P3: AG = A*G ; tls = G*wk0 ----
  {
    const int l = t >> 4, lp = t & 15;
    float a[16];
    #pragma unroll
    for (int q = 0; q < 4; ++q)
      *(float4*)(a + q*4) = *(const float4*)(ws + WS_A + l*16 + q*4);
    float s = 0.f;
    #pragma unroll
    for (int k = 0; k < 16; ++k) s += a[k] * Gs[k*16 + lp];
    AGs[t] = s;
  }
  if (t < 16) {
    float s = 0.f;
    #pragma unroll
    for (int q = 0; q < 4; ++q) {
      const float4 g = *(const float4*)(Gs + t*16 + q*4);
      const float4 wk = *(const float4*)(ws + WS_WK0 + q*4);
      s += g.x*wk.x + g.y*wk.y + g.z*wk.z + g.w*wk.w;
    }
    tls[t] = s;
  }
  bar_lds();  // B3

  // ---- P4: M = X*AG -> Abf kt2-3 ; c0s ----
  {
    const s16x8 xlo = *(const s16x8*)&Xb[xc*40];
    const s16x8 xhi = *(const s16x8*)&Xb[xc*40 + 8];
    float4 m = make_float4(0.f, 0.f, 0.f, 0.f);
    #pragma unroll
    for (int i = 0; i < 8; ++i) {
      const float xv = bf2f(xlo[i]);
      const float4 g = *(const float4*)(AGs + i*16 + xl0);
      m.x += xv*g.x; m.y += xv*g.y; m.z += xv*g.z; m.w += xv*g.w;
    }
    #pragma unroll
    for (int i = 0; i < 8; ++i) {
      const float xv = bf2f(xhi[i]);
      const float4 g = *(const float4*)(AGs + (8+i)*16 + xl0);
      m.x += xv*g.x; m.y += xv*g.y; m.z += xv*g.z; m.w += xv*g.w;
    }
    s16x4 mb;
    mb[0] = bf16b(m.x); mb[1] = bf16b(m.y); mb[2] = bf16b(m.z); mb[3] = bf16b(m.w);
    *(s16x4*)&Abf[(((2 + (xl0>>3))*64 + xc) << 3) + (xl0 & 4)] = mb;
  }
  {
    float tl[16], e[16];
    #pragma unroll
    for (int q = 0; q < 4; ++q) {
      *(float4*)(tl + q*4) = *(const float4*)(tls + q*4);
      *(float4*)(e + q*4) = *(const float4*)(ws + WS_E0 + t*16 + q*4);
    }
    float s = pb[t];
    #pragma unroll
    for (int l = 0; l < 16; ++l) s += tl[l] * e[l];
    c0s[t] = s;
  }
  bar_lds();  // B4

  // ---- P5: MFMA, A = acts (rows c), B = weights (cols d); K = 160 ----
  f32x4 acc[4][4] = {};                  // [mi: c-tile][nt: d-tile]
  #pragma unroll
  for (int ks = 0; ks < 5; ++ks) {
    s16x8 af[4], bf_[4];
    #pragma unroll
    for (int mi = 0; mi < 4; ++mi)
      af[mi] = *(const s16x8*)&Abf[(((ks*4 + lq)*64) + mi*16 + lr) << 3];
    #pragma unroll
    for (int nt = 0; nt < 4; ++nt)
      bf_[nt] = *(const s16x8*)&BTW[(n0 + nt*16 + lr)*160 + ks*32 + lq*8];
    #pragma unroll
    for (int mi = 0; mi < 4; ++mi)
      #pragma unroll
      for (int nt = 0; nt < 4; ++nt)
        acc[mi][nt] = __builtin_amdgcn_mfma_f32_16x16x32_bf16(af[mi], bf_[nt], acc[mi][nt], 0, 0, 0);
  }

  // ---- epilogue (R11 order) with NON-TEMPORAL stores: output is written
  //      once and never re-read -- bypass L2 allocation so the 134MB write
  //      stream stops evicting the hot BT read set ----
  #pragma unroll
  for (int nt = 0; nt < 4; ++nt) {
    const int d = n0 + nt*16 + lr;
    const float cc = c0s[d];
    #pragma unroll
    for (int mi = 0; mi < 4; ++mi) {
      #pragma unroll
      for (int r = 0; r < 4; ++r) {
        const int c = mi*16 + lq*4 + r;
        __builtin_nontemporal_store(acc[mi][nt][r] + cc,
                                    out + (((b*64 + c)*128 + p) << 8) + d);
      }
    }
  }
}

extern "C" void kernel_launch(void* const* d_in, const int* in_sizes, int n_in,
                              void* d_out, int out_size, void* d_ws, size_t ws_size,
                              hipStream_t stream) {
  const float* x  = (const float*)d_in[0];
  const float* Wq = (const float*)d_in[1];
  const float* Wk = (const float*)d_in[2];
  const float* Wv = (const float*)d_in[3];
  const float* fw = (const float*)d_in[4];
  const float* fb = (const float*)d_in[5];
  const float* pw = (const float*)d_in[6];
  const float* pb = (const float*)d_in[7];
  float* out = (float*)d_out;
  float* ws  = (float*)d_ws;   // needs 24848 floats ~ 100 KB

  pre_kernel<<<18, 512, 0, stream>>>(Wq, Wk, Wv, pw, ws);
  main_kernel<<<16*128, 256, 0, stream>>>(x, fw, fb, pb, ws, out);
}

// Round 19
// 51.778 us; speedup vs baseline: 1.0712x; 1.0712x over previous
//
#include <hip/hip_runtime.h>
#include <hip/hip_bf16.h>

// B=16, C=64, P=128, L=16, D=256, NPF=256, NRFF=128, FEAT=656
// ws layout (float slots):
#define WS_WK0   0        // 16     wk0 = Wk0^T q0
#define WS_A     16       // 256    A = Wq1^T Wk1
#define WS_E0    272      // 4096   E0 = Pp0 * Wv0  (256 x 16), f32 (for c0)
#define WS_BT    4368     // 20480 f32-slots = 40960 ushort: BTall[256][160] bf16
//   BTall[d][kk]: 0..15 Px; 16..31 E1; 32..95 Psin; 96..159 Pcos

typedef float f32x4 __attribute__((ext_vector_type(4)));
typedef short s16x8 __attribute__((ext_vector_type(8)));
typedef short s16x4 __attribute__((ext_vector_type(4)));

static __device__ __forceinline__ short bf16b(float f) {
  __hip_bfloat16 h = __float2bfloat16(f);
  return __builtin_bit_cast(short, h);
}
static __device__ __forceinline__ float bf2f(short s) {
  unsigned u = ((unsigned)(unsigned short)s) << 16;
  return __builtin_bit_cast(float, u);
}

// lgkmcnt-only barrier: orders LDS producer->consumer without draining vmcnt.
static __device__ __forceinline__ void bar_lds() {
  asm volatile("s_waitcnt lgkmcnt(0)\n\ts_barrier" ::: "memory");
}

__global__ __launch_bounds__(512)
void pre_kernel(const float* __restrict__ Wq, const float* __restrict__ Wk,
                const float* __restrict__ Wv, const float* __restrict__ pw,
                float* __restrict__ ws)
{
  __shared__ float lds[8704];
  const int t = threadIdx.x;
  const int blk = blockIdx.x;
  ushort* bt = (ushort*)(ws + WS_BT);

  if (blk == 0) {
    {
      const int d = t >> 1;
      const int lb = (t & 1) * 8;
      #pragma unroll
      for (int h = 0; h < 2; ++h) {
        const float4 vq = *(const float4*)(Wq + 4096 + t*8 + h*4);
        lds[(lb+h*4+0)*256 + d] = vq.x;
        lds[(lb+h*4+1)*256 + d] = vq.y;
        lds[(lb+h*4+2)*256 + d] = vq.z;
        lds[(lb+h*4+3)*256 + d] = vq.w;
        const float4 vk = *(const float4*)(Wk + 4096 + t*8 + h*4);
        lds[4096 + (lb+h*4+0)*256 + d] = vk.x;
        lds[4096 + (lb+h*4+1)*256 + d] = vk.y;
        lds[4096 + (lb+h*4+2)*256 + d] = vk.z;
        lds[4096 + (lb+h*4+3)*256 + d] = vk.w;
      }
    }
    if (t < 256) {
      float s = 0.f;
      #pragma unroll
      for (int q = 0; q < 4; ++q) {
        const float4 v = *(const float4*)(Wq + t*16 + q*4);
        s += v.x + v.y + v.z + v.w;           // q0[d]
      }
      lds[8192 + t] = s;
    }
    __syncthreads();
    if (t < 256) {
      const int l1 = t >> 4, l2 = t & 15;
      const float* r1 = lds + l1*256;
      const float* r2 = lds + 4096 + l2*256;
      float s = 0.f;
      #pragma unroll 8
      for (int dq = 0; dq < 64; ++dq) {
        const float4 a = *(const float4*)(r1 + dq*4);
        const float4 b = *(const float4*)(r2 + dq*4);
        s += a.x*b.x + a.y*b.y + a.z*b.z + a.w*b.w;    // A[l1,l2]
      }
      ws[WS_A + t] = s;
    }
    if (t < 256) {                 // wk0 partial sums
      const int l = t & 15, ch = t >> 4;
      float s = 0.f;
      #pragma unroll
      for (int i = 0; i < 16; ++i)
        s += lds[8192 + ch*16 + i] * Wk[(ch*16 + i)*16 + l];
      lds[8448 + t] = s;
    }
    __syncthreads();
    if (t < 16) {
      float s = 0.f;
      #pragma unroll
      for (int ch = 0; ch < 16; ++ch) s += lds[8448 + ch*16 + t];
      ws[WS_WK0 + t] = s;          // wk0[l]
    }
  } else if (blk <= 16) {
    const int deg = (blk <= 8) ? 0 : 1;
    {
      const int f = t >> 1;
      const int lb = (t & 1) * 8;
      #pragma unroll
      for (int h = 0; h < 2; ++h) {
        const float4 v = *(const float4*)(Wv + deg*4096 + t*8 + h*4);
        lds[(lb+h*4+0)*256 + f] = v.x;
        lds[(lb+h*4+1)*256 + f] = v.y;
        lds[(lb+h*4+2)*256 + f] = v.z;
        lds[(lb+h*4+3)*256 + f] = v.w;
      }
    }
    __syncthreads();
    const int d = ((blk-1) & 7)*32 + (t >> 4);
    const int l = t & 15;
    const float* pr = pw + d*656 + (deg ? 272 : 16);
    const float* wv = lds + l*256;
    float s = 0.f;
    #pragma unroll 8
    for (int fq = 0; fq < 64; ++fq) {
      const float4 a = *(const float4*)(pr + fq*4);
      const float4 b = *(const float4*)(wv + fq*4);
      s += a.x*b.x + a.y*b.y + a.z*b.z + a.w*b.w;
    }
    if (deg == 0) {
      ws[WS_E0 + d*16 + l] = s;
      bt[d*160 + l] = (ushort)bf16b(pw[d*656 + l]);
    } else {
      bt[d*160 + 16 + l] = (ushort)bf16b(s);
    }
  } else {
    #pragma unroll 4
    for (int k = 0; k < 64; ++k) {
      const int d = k*4 + (t >> 7);
      const int j = t & 127;
      const float v = (j < 64) ? pw[d*656 + 528 + j] : pw[d*656 + 592 + (j-64)];
      bt[d*160 + 32 + j] = (ushort)bf16b(v);
    }
  }
}

__global__ __launch_bounds__(256, 2)
void main_kernel(const float* __restrict__ x, const float* __restrict__ fw,
                 const float* __restrict__ fb, const float* __restrict__ pb,
                 const float* __restrict__ ws, float* __restrict__ out)
{
  __shared__ short Xb[64*40];    // bf16 X [c][k], 80B rows; k in [16,32) zero
  __shared__ short XbT[16*72];   // bf16 X^T [l][c], 144B rows
  __shared__ short Fwt[64*40];   // bf16 fw^T [j][k]; k>=16 zero
  __shared__ float fbs[64];
  __shared__ float Gs[256];      // G = X^T X (f32, from MFMA)
  __shared__ float AGs[256];     // AG = A * G
  __shared__ float tls[16];      // G * wk0
  __shared__ float c0s[256];     // pb + E0 * tls
  __shared__ __align__(16) short Abf[20*64*8];
  // bf16 acts [kt][c][8]: kt0-1=x, kt2-3=M, kt4-11=sin, kt12-19=cos
  // after P5 reused as f32 tile [16][260] for the contiguous-store transpose
  // ~36.6 KB

  const int t = threadIdx.x;
  const int b = blockIdx.x >> 7;
  const int p = blockIdx.x & 127;

  const int lane = t & 63, w = t >> 6;
  const int n0 = w << 6;                    // wave's d-offset
  const int lr = lane & 15, lq = lane >> 4;
  const int xc = t >> 2, xl0 = (t & 3) * 4;
  const ushort* BTW = (const ushort*)(ws + WS_BT);

  // ---- P1: stage X (3 bf16 layouts) + fw^T + fb ----
  {
    const float4 v = *(const float4*)(x + (((b*64 + xc)*128 + p) << 4) + xl0);
    s16x4 xb;
    xb[0] = bf16b(v.x); xb[1] = bf16b(v.y); xb[2] = bf16b(v.z); xb[3] = bf16b(v.w);
    s16x4 z; z[0] = 0; z[1] = 0; z[2] = 0; z[3] = 0;
    *(s16x4*)&Xb[xc*40 + xl0] = xb;
    *(s16x4*)&Xb[xc*40 + 16 + xl0] = z;            // zero-pad k 16..31
    XbT[(xl0+0)*72 + xc] = xb[0];
    XbT[(xl0+1)*72 + xc] = xb[1];
    XbT[(xl0+2)*72 + xc] = xb[2];
    XbT[(xl0+3)*72 + xc] = xb[3];
    *(s16x4*)&Abf[(((xl0>>3)*64 + xc) << 3) + (xl0 & 4)] = xb;
    // fw^T: thread covers fw row l = t>>4, cols j0..j0+3
    const int l = t >> 4, j0 = (t & 15) * 4;
    const float4 f = *(const float4*)(fw + l*64 + j0);
    Fwt[(j0+0)*40 + l] = (short)bf16b(f.x);
    Fwt[(j0+1)*40 + l] = (short)bf16b(f.y);
    Fwt[(j0+2)*40 + l] = (short)bf16b(f.z);
    Fwt[(j0+3)*40 + l] = (short)bf16b(f.w);
    *(s16x4*)&Fwt[(t>>2)*40 + 16 + (t & 3)*4] = z; // zero-pad k 16..31
    if (t < 16) *(float4*)(fbs + t*4) = *(const float4*)(fb + t*4);
  }
  bar_lds();  // B1

  // ---- P2a (wave 0): G = X^T X via MFMA, A = B = XbT fragment ----
  if (w == 0) {
    f32x4 g = {};
    #pragma unroll
    for (int ks = 0; ks < 2; ++ks) {
      const s16x8 xa = *(const s16x8*)&XbT[lr*72 + ks*32 + lq*8];
      g = __builtin_amdgcn_mfma_f32_16x16x32_bf16(xa, xa, g, 0, 0, 0);
    }
    #pragma unroll
    for (int r = 0; r < 4; ++r) Gs[(lq*4 + r)*16 + lr] = g[r];
  }
  // ---- P2b (all waves): wx = X*fw via MFMA; j-block = w; sincos -> Abf ----
  {
    s16x8 xa[4];
    #pragma unroll
    for (int mi = 0; mi < 4; ++mi)
      xa[mi] = *(const s16x8*)&Xb[(mi*16 + lr)*40 + lq*8];
    const s16x8 fwf = *(const s16x8*)&Fwt[(w*16 + lr)*40 + lq*8];
    f32x4 wa[4];
    #pragma unroll
    for (int mi = 0; mi < 4; ++mi) {
      f32x4 zz = {};
      wa[mi] = __builtin_amdgcn_mfma_f32_16x16x32_bf16(xa[mi], fwf, zz, 0, 0, 0);
    }
    const float fbj = fbs[w*16 + lr];          // lane's j = w*16 + lr
    const int ktS = 4 + 2*w + (lr >> 3);       // sin row: 4 + j/8
    const int ktC = ktS + 8;                   // cos row
    const int e = lr & 7;                      // j % 8
    #pragma unroll
    for (int mi = 0; mi < 4; ++mi) {
      #pragma unroll
      for (int r = 0; r < 4; ++r) {
        const int c = mi*16 + lq*4 + r;        // D row = c
        float sv, cv;
        __sincosf(wa[mi][r] + fbj, &sv, &cv);
        Abf[(ktS*64 + c)*8 + e] = bf16b(sv);
        Abf[(ktC*64 + c)*8 + e] = bf16b(cv);
      }
    }
  }
  bar_lds();  // B2

  // ---- P3: AG = A*G ; tls = G*wk0 ----
  {
    const int l = t >> 4, lp = t & 15;
    float a[16];
    #pragma unroll
    for (int q = 0; q < 4; ++q)
      *(float4*)(a + q*4) = *(const float4*)(ws + WS_A + l*16 + q*4);
    float s = 0.f;
    #pragma unroll
    for (int k = 0; k < 16; ++k) s += a[k] * Gs[k*16 + lp];
    AGs[t] = s;
  }
  if (t < 16) {
    float s = 0.f;
    #pragma unroll
    for (int q = 0; q < 4; ++q) {
      const float4 g = *(const float4*)(Gs + t*16 + q*4);
      const float4 wk = *(const float4*)(ws + WS_WK0 + q*4);
      s += g.x*wk.x + g.y*wk.y + g.z*wk.z + g.w*wk.w;
    }
    tls[t] = s;
  }
  bar_lds();  // B3

  // ---- P4: M = X*AG -> Abf kt2-3 ; c0s ----
  {
    const s16x8 xlo = *(const s16x8*)&Xb[xc*40];
    const s16x8 xhi = *(const s16x8*)&Xb[xc*40 + 8];
    float4 m = make_float4(0.f, 0.f, 0.f, 0.f);
    #pragma unroll
    for (int i = 0; i < 8; ++i) {
      const float xv = bf2f(xlo[i]);
      const float4 g = *(const float4*)(AGs + i*16 + xl0);
      m.x += xv*g.x; m.y += xv*g.y; m.z += xv*g.z; m.w += xv*g.w;
    }
    #pragma unroll
    for (int i = 0; i < 8; ++i) {
      const float xv = bf2f(xhi[i]);
      const float4 g = *(const float4*)(AGs + (8+i)*16 + xl0);
      m.x += xv*g.x; m.y += xv*g.y; m.z += xv*g.z; m.w += xv*g.w;
    }
    s16x4 mb;
    mb[0] = bf16b(m.x); mb[1] = bf16b(m.y); mb[2] = bf16b(m.z); mb[3] = bf16b(m.w);
    *(s16x4*)&Abf[(((2 + (xl0>>3))*64 + xc) << 3) + (xl0 & 4)] = mb;
  }
  {
    float tl[16], e[16];
    #pragma unroll
    for (int q = 0; q < 4; ++q) {
      *(float4*)(tl + q*4) = *(const float4*)(tls + q*4);
      *(float4*)(e + q*4) = *(const float4*)(ws + WS_E0 + t*16 + q*4);
    }
    float s = pb[t];
    #pragma unroll
    for (int l = 0; l < 16; ++l) s += tl[l] * e[l];
    c0s[t] = s;
  }
  bar_lds();  // B4

  // ---- P5: MFMA, A = acts (rows c), B = weights (cols d); K = 160 ----
  f32x4 acc[4][4] = {};                  // [mi: c-tile][nt: d-tile]
  #pragma unroll
  for (int ks = 0; ks < 5; ++ks) {
    s16x8 af[4], bf_[4];
    #pragma unroll
    for (int mi = 0; mi < 4; ++mi)
      af[mi] = *(const s16x8*)&Abf[(((ks*4 + lq)*64) + mi*16 + lr) << 3];
    #pragma unroll
    for (int nt = 0; nt < 4; ++nt)
      bf_[nt] = *(const s16x8*)&BTW[(n0 + nt*16 + lr)*160 + ks*32 + lq*8];
    #pragma unroll
    for (int mi = 0; mi < 4; ++mi)
      #pragma unroll
      for (int nt = 0; nt < 4; ++nt)
        acc[mi][nt] = __builtin_amdgcn_mfma_f32_16x16x32_bf16(af[mi], bf_[nt], acc[mi][nt], 0, 0, 0);
  }

  // ---- epilogue: transpose via LDS (reuse Abf) -> fully-contiguous stores.
  //      Each wave ends up storing complete 1KB output rows (lane i -> d=4i..4i+3),
  //      the fill kernel's 6.9 TB/s pattern, instead of 4x64B scattered segments.
  bar_lds();  // all waves finished reading Abf in P5
  float* tile = (float*)Abf;   // [16][260] f32, pad 260 -> benign 2-way bank alias
  #pragma unroll
  for (int mi = 0; mi < 4; ++mi) {
    // deposit this wave's 64 d-columns of c-group mi (rows lq*4+r)
    #pragma unroll
    for (int nt = 0; nt < 4; ++nt) {
      const int d = n0 + nt*16 + lr;
      const float cc = c0s[d];
      #pragma unroll
      for (int r = 0; r < 4; ++r)
        tile[(lq*4 + r)*260 + d] = acc[mi][nt][r] + cc;
    }
    bar_lds();
    // cooperative contiguous store: 4 rounds x 4 rows; wave w stores row
    // round*4+w as one 1KB contiguous burst (64 lanes x float4)
    #pragma unroll
    for (int round = 0; round < 4; ++round) {
      const int cr = round*4 + w;
      const int c = mi*16 + cr;
      const float4 v = *(const float4*)&tile[cr*260 + lane*4];
      *(float4*)(out + (((b*64 + c)*128 + p) << 8) + lane*4) = v;
    }
    bar_lds();  // reads done before next mi overwrites tile
  }
}

extern "C" void kernel_launch(void* const* d_in, const int* in_sizes, int n_in,
                              void* d_out, int out_size, void* d_ws, size_t ws_size,
                              hipStream_t stream) {
  const float* x  = (const float*)d_in[0];
  const float* Wq = (const float*)d_in[1];
  const float* Wk = (const float*)d_in[2];
  const float* Wv = (const float*)d_in[3];
  const float* fw = (const float*)d_in[4];
  const float* fb = (const float*)d_in[5];
  const float* pw = (const float*)d_in[6];
  const float* pb = (const float*)d_in[7];
  float* out = (float*)d_out;
  float* ws  = (float*)d_ws;   // needs 24848 floats ~ 100 KB

  pre_kernel<<<18, 512, 0, stream>>>(Wq, Wk, Wv, pw, ws);
  main_kernel<<<16*128, 256, 0, stream>>>(x, fw, fb, pb, ws, out);
}

// Round 20
// 46.487 us; speedup vs baseline: 1.1932x; 1.1138x over previous
//
#include <hip/hip_runtime.h>
#include <hip/hip_bf16.h>

// B=16, C=64, P=128, L=16, D=256, NPF=256, NRFF=128, FEAT=656
// ws layout (float slots):
#define WS_WK0   0        // 16     wk0 = Wk0^T q0
#define WS_A     16       // 256    A = Wq1^T Wk1
#define WS_E0    272      // 4096   E0 = Pp0 * Wv0  (256 x 16), f32 (for c0)
#define WS_BT    4368     // 20480 f32-slots = 40960 ushort: BTall[256][160] bf16
//   BTall[d][kk]: 0..15 Px; 16..31 E1; 32..95 Psin; 96..159 Pcos

typedef float f32x4 __attribute__((ext_vector_type(4)));
typedef short s16x8 __attribute__((ext_vector_type(8)));
typedef short s16x4 __attribute__((ext_vector_type(4)));

static __device__ __forceinline__ short bf16b(float f) {
  __hip_bfloat16 h = __float2bfloat16(f);
  return __builtin_bit_cast(short, h);
}
static __device__ __forceinline__ float bf2f(short s) {
  unsigned u = ((unsigned)(unsigned short)s) << 16;
  return __builtin_bit_cast(float, u);
}

// lgkmcnt-only barrier: orders LDS producer->consumer without draining vmcnt.
static __device__ __forceinline__ void bar_lds() {
  asm volatile("s_waitcnt lgkmcnt(0)\n\ts_barrier" ::: "memory");
}

// Regridded 18 -> 73 blocks: the E0/E1 dot-products (the serial-latency
// dominant part) spread over 64 blocks (8 d's each) instead of 16 (32 d's).
__global__ __launch_bounds__(512)
void pre_kernel(const float* __restrict__ Wq, const float* __restrict__ Wk,
                const float* __restrict__ Wv, const float* __restrict__ pw,
                float* __restrict__ ws)
{
  __shared__ float lds[8704];
  const int t = threadIdx.x;
  const int blk = blockIdx.x;
  ushort* bt = (ushort*)(ws + WS_BT);

  if (blk == 0) {
    {
      const int d = t >> 1;
      const int lb = (t & 1) * 8;
      #pragma unroll
      for (int h = 0; h < 2; ++h) {
        const float4 vq = *(const float4*)(Wq + 4096 + t*8 + h*4);
        lds[(lb+h*4+0)*256 + d] = vq.x;
        lds[(lb+h*4+1)*256 + d] = vq.y;
        lds[(lb+h*4+2)*256 + d] = vq.z;
        lds[(lb+h*4+3)*256 + d] = vq.w;
        const float4 vk = *(const float4*)(Wk + 4096 + t*8 + h*4);
        lds[4096 + (lb+h*4+0)*256 + d] = vk.x;
        lds[4096 + (lb+h*4+1)*256 + d] = vk.y;
        lds[4096 + (lb+h*4+2)*256 + d] = vk.z;
        lds[4096 + (lb+h*4+3)*256 + d] = vk.w;
      }
    }
    if (t < 256) {
      float s = 0.f;
      #pragma unroll
      for (int q = 0; q < 4; ++q) {
        const float4 v = *(const float4*)(Wq + t*16 + q*4);
        s += v.x + v.y + v.z + v.w;           // q0[d]
      }
      lds[8192 + t] = s;
    }
    __syncthreads();
    if (t < 256) {
      const int l1 = t >> 4, l2 = t & 15;
      const float* r1 = lds + l1*256;
      const float* r2 = lds + 4096 + l2*256;
      float s = 0.f;
      #pragma unroll 8
      for (int dq = 0; dq < 64; ++dq) {
        const float4 a = *(const float4*)(r1 + dq*4);
        const float4 b = *(const float4*)(r2 + dq*4);
        s += a.x*b.x + a.y*b.y + a.z*b.z + a.w*b.w;    // A[l1,l2]
      }
      ws[WS_A + t] = s;
    }
    if (t < 256) {                 // wk0 partial sums
      const int l = t & 15, ch = t >> 4;
      float s = 0.f;
      #pragma unroll
      for (int i = 0; i < 16; ++i)
        s += lds[8192 + ch*16 + i] * Wk[(ch*16 + i)*16 + l];
      lds[8448 + t] = s;
    }
    __syncthreads();
    if (t < 16) {
      float s = 0.f;
      #pragma unroll
      for (int ch = 0; ch < 16; ++ch) s += lds[8448 + ch*16 + t];
      ws[WS_WK0 + t] = s;          // wk0[l]
    }
  } else if (blk <= 64) {
    // E0 (blk 1..32) / E1 (blk 33..64): 8 d's per block
    const int deg = (blk <= 32) ? 0 : 1;
    {
      const int f = t >> 1;
      const int lb = (t & 1) * 8;
      #pragma unroll
      for (int h = 0; h < 2; ++h) {
        const float4 v = *(const float4*)(Wv + deg*4096 + t*8 + h*4);
        lds[(lb+h*4+0)*256 + f] = v.x;
        lds[(lb+h*4+1)*256 + f] = v.y;
        lds[(lb+h*4+2)*256 + f] = v.z;
        lds[(lb+h*4+3)*256 + f] = v.w;
      }
    }
    __syncthreads();
    if (t < 128) {
      const int d = ((blk-1) & 31)*8 + (t >> 4);
      const int l = t & 15;
      const float* pr = pw + d*656 + (deg ? 272 : 16);
      const float* wv = lds + l*256;
      float s = 0.f;
      #pragma unroll 8
      for (int fq = 0; fq < 64; ++fq) {
        const float4 a = *(const float4*)(pr + fq*4);
        const float4 b = *(const float4*)(wv + fq*4);
        s += a.x*b.x + a.y*b.y + a.z*b.z + a.w*b.w;
      }
      if (deg == 0) {
        ws[WS_E0 + d*16 + l] = s;
        bt[d*160 + l] = (ushort)bf16b(pw[d*656 + l]);
      } else {
        bt[d*160 + 16 + l] = (ushort)bf16b(s);
      }
    }
  } else {
    // RFF projection weights: blk 65..72, 32 d's each (coalesced along j)
    const int idx = blk - 65;
    #pragma unroll
    for (int k = 0; k < 8; ++k) {
      const int d = idx*32 + k*4 + (t >> 7);
      const int j = t & 127;
      const float v = (j < 64) ? pw[d*656 + 528 + j] : pw[d*656 + 592 + (j-64)];
      bt[d*160 + 32 + j] = (ushort)bf16b(v);
    }
  }
}

__global__ __launch_bounds__(256, 2)
void main_kernel(const float* __restrict__ x, const float* __restrict__ fw,
                 const float* __restrict__ fb, const float* __restrict__ pb,
                 const float* __restrict__ ws, float* __restrict__ out)
{
  __shared__ short Xb[64*40];    // bf16 X [c][k], 80B rows; k in [16,32) zero
  __shared__ short XbT[16*72];   // bf16 X^T [l][c], 144B rows
  __shared__ short Fwt[64*40];   // bf16 fw^T [j][k]; k>=16 zero
  __shared__ float fbs[64];
  __shared__ float Gs[256];      // G = X^T X (f32, from MFMA)
  __shared__ float AGs[256];     // AG = A * G
  __shared__ float tls[16];      // G * wk0
  __shared__ float c0s[256];     // pb + E0 * tls
  __shared__ __align__(16) short Abf[20*64*8];
  // bf16 acts [kt][c][8]: kt0-1=x, kt2-3=M, kt4-11=sin, kt12-19=cos
  // after P5 reused as f32 tile [16][260] for the contiguous-store transpose
  // ~36.6 KB

  const int t = threadIdx.x;
  const int b = blockIdx.x >> 7;
  const int p = blockIdx.x & 127;

  const int lane = t & 63, w = t >> 6;
  const int n0 = w << 6;                    // wave's d-offset
  const int lr = lane & 15, lq = lane >> 4;
  const int xc = t >> 2, xl0 = (t & 3) * 4;
  const ushort* BTW = (const ushort*)(ws + WS_BT);

  // ---- P1: stage X (3 bf16 layouts) + fw^T + fb ----
  {
    const float4 v = *(const float4*)(x + (((b*64 + xc)*128 + p) << 4) + xl0);
    s16x4 xb;
    xb[0] = bf16b(v.x); xb[1] = bf16b(v.y); xb[2] = bf16b(v.z); xb[3] = bf16b(v.w);
    s16x4 z; z[0] = 0; z[1] = 0; z[2] = 0; z[3] = 0;
    *(s16x4*)&Xb[xc*40 + xl0] = xb;
    *(s16x4*)&Xb[xc*40 + 16 + xl0] = z;            // zero-pad k 16..31
    XbT[(xl0+0)*72 + xc] = xb[0];
    XbT[(xl0+1)*72 + xc] = xb[1];
    XbT[(xl0+2)*72 + xc] = xb[2];
    XbT[(xl0+3)*72 + xc] = xb[3];
    *(s16x4*)&Abf[(((xl0>>3)*64 + xc) << 3) + (xl0 & 4)] = xb;
    // fw^T: thread covers fw row l = t>>4, cols j0..j0+3
    const int l = t >> 4, j0 = (t & 15) * 4;
    const float4 f = *(const float4*)(fw + l*64 + j0);
    Fwt[(j0+0)*40 + l] = (short)bf16b(f.x);
    Fwt[(j0+1)*40 + l] = (short)bf16b(f.y);
    Fwt[(j0+2)*40 + l] = (short)bf16b(f.z);
    Fwt[(j0+3)*40 + l] = (short)bf16b(f.w);
    *(s16x4*)&Fwt[(t>>2)*40 + 16 + (t & 3)*4] = z; // zero-pad k 16..31
    if (t < 16) *(float4*)(fbs + t*4) = *(const float4*)(fb + t*4);
  }
  bar_lds();  // B1

  // ---- P2a (wave 0): G = X^T X via MFMA, A = B = XbT fragment ----
  if (w == 0) {
    f32x4 g = {};
    #pragma unroll
    for (int ks = 0; ks < 2; ++ks) {
      const s16x8 xa = *(const s16x8*)&XbT[lr*72 + ks*32 + lq*8];
      g = __builtin_amdgcn_mfma_f32_16x16x32_bf16(xa, xa, g, 0, 0, 0);
    }
    #pragma unroll
    for (int r = 0; r < 4; ++r) Gs[(lq*4 + r)*16 + lr] = g[r];
  }
  // ---- P2b (all waves): wx = X*fw via MFMA; j-block = w; sincos -> Abf ----
  {
    s16x8 xa[4];
    #pragma unroll
    for (int mi = 0; mi < 4; ++mi)
      xa[mi] = *(const s16x8*)&Xb[(mi*16 + lr)*40 + lq*8];
    const s16x8 fwf = *(const s16x8*)&Fwt[(w*16 + lr)*40 + lq*8];
    f32x4 wa[4];
    #pragma unroll
    for (int mi = 0; mi < 4; ++mi) {
      f32x4 zz = {};
      wa[mi] = __builtin_amdgcn_mfma_f32_16x16x32_bf16(xa[mi], fwf, zz, 0, 0, 0);
    }
    const float fbj = fbs[w*16 + lr];          // lane's j = w*16 + lr
    const int ktS = 4 + 2*w + (lr >> 3);       // sin row: 4 + j/8
    const int ktC = ktS + 8;                   // cos row
    const int e = lr & 7;                      // j % 8
    #pragma unroll
    for (int mi = 0; mi < 4; ++mi) {
      #pragma unroll
      for (int r = 0; r < 4; ++r) {
        const int c = mi*16 + lq*4 + r;        // D row = c
        float sv, cv;
        __sincosf(wa[mi][r] + fbj, &sv, &cv);
        Abf[(ktS*64 + c)*8 + e] = bf16b(sv);
        Abf[(ktC*64 + c)*8 + e] = bf16b(cv);
      }
    }
  }
  bar_lds();  // B2

  // ---- P3: AG = A*G ; tls = G*wk0 ----
  {
    const int l = t >> 4, lp = t & 15;
    float a[16];
    #pragma unroll
    for (int q = 0; q < 4; ++q)
      *(float4*)(a + q*4) = *(const float4*)(ws + WS_A + l*16 + q*4);
    float s = 0.f;
    #pragma unroll
    for (int k = 0; k < 16; ++k) s += a[k] * Gs[k*16 + lp];
    AGs[t] = s;
  }
  if (t < 16) {
    float s = 0.f;
    #pragma unroll
    for (int q = 0; q < 4; ++q) {
      const float4 g = *(const float4*)(Gs + t*16 + q*4);
      const float4 wk = *(const float4*)(ws + WS_WK0 + q*4);
      s += g.x*wk.x + g.y*wk.y + g.z*wk.z + g.w*wk.w;
    }
    tls[t] = s;
  }
  bar_lds();  // B3

  // ---- P4: M = X*AG -> Abf kt2-3 ; c0s ----
  {
    const s16x8 xlo = *(const s16x8*)&Xb[xc*40];
    const s16x8 xhi = *(const s16x8*)&Xb[xc*40 + 8];
    float4 m = make_float4(0.f, 0.f, 0.f, 0.f);
    #pragma unroll
    for (int i = 0; i < 8; ++i) {
      const float xv = bf2f(xlo[i]);
      const float4 g = *(const float4*)(AGs + i*16 + xl0);
      m.x += xv*g.x; m.y += xv*g.y; m.z += xv*g.z; m.w += xv*g.w;
    }
    #pragma unroll
    for (int i = 0; i < 8; ++i) {
      const float xv = bf2f(xhi[i]);
      const float4 g = *(const float4*)(AGs + (8+i)*16 + xl0);
      m.x += xv*g.x; m.y += xv*g.y; m.z += xv*g.z; m.w += xv*g.w;
    }
    s16x4 mb;
    mb[0] = bf16b(m.x); mb[1] = bf16b(m.y); mb[2] = bf16b(m.z); mb[3] = bf16b(m.w);
    *(s16x4*)&Abf[(((2 + (xl0>>3))*64 + xc) << 3) + (xl0 & 4)] = mb;
  }
  {
    float tl[16], e[16];
    #pragma unroll
    for (int q = 0; q < 4; ++q) {
      *(float4*)(tl + q*4) = *(const float4*)(tls + q*4);
      *(float4*)(e + q*4) = *(const float4*)(ws + WS_E0 + t*16 + q*4);
    }
    float s = pb[t];
    #pragma unroll
    for (int l = 0; l < 16; ++l) s += tl[l] * e[l];
    c0s[t] = s;
  }
  bar_lds();  // B4

  // ---- P5: MFMA, A = acts (rows c), B = weights (cols d); K = 160 ----
  f32x4 acc[4][4] = {};                  // [mi: c-tile][nt: d-tile]
  #pragma unroll
  for (int ks = 0; ks < 5; ++ks) {
    s16x8 af[4], bf_[4];
    #pragma unroll
    for (int mi = 0; mi < 4; ++mi)
      af[mi] = *(const s16x8*)&Abf[(((ks*4 + lq)*64) + mi*16 + lr) << 3];
    #pragma unroll
    for (int nt = 0; nt < 4; ++nt)
      bf_[nt] = *(const s16x8*)&BTW[(n0 + nt*16 + lr)*160 + ks*32 + lq*8];
    #pragma unroll
    for (int mi = 0; mi < 4; ++mi)
      #pragma unroll
      for (int nt = 0; nt < 4; ++nt)
        acc[mi][nt] = __builtin_amdgcn_mfma_f32_16x16x32_bf16(af[mi], bf_[nt], acc[mi][nt], 0, 0, 0);
  }

  // ---- epilogue: transpose via LDS (reuse Abf) -> fully-contiguous stores ----
  bar_lds();  // all waves finished reading Abf in P5
  float* tile = (float*)Abf;   // [16][260] f32, pad 260 -> benign 2-way bank alias
  #pragma unroll
  for (int mi = 0; mi < 4; ++mi) {
    #pragma unroll
    for (int nt = 0; nt < 4; ++nt) {
      const int d = n0 + nt*16 + lr;
      const float cc = c0s[d];
      #pragma unroll
      for (int r = 0; r < 4; ++r)
        tile[(lq*4 + r)*260 + d] = acc[mi][nt][r] + cc;
    }
    bar_lds();
    #pragma unroll
    for (int round = 0; round < 4; ++round) {
      const int cr = round*4 + w;
      const int c = mi*16 + cr;
      const float4 v = *(const float4*)&tile[cr*260 + lane*4];
      *(float4*)(out + (((b*64 + c)*128 + p) << 8) + lane*4) = v;
    }
    bar_lds();  // reads done before next mi overwrites tile
  }
}

extern "C" void kernel_launch(void* const* d_in, const int* in_sizes, int n_in,
                              void* d_out, int out_size, void* d_ws, size_t ws_size,
                              hipStream_t stream) {
  const float* x  = (const float*)d_in[0];
  const float* Wq = (const float*)d_in[1];
  const float* Wk = (const float*)d_in[2];
  const float* Wv = (const float*)d_in[3];
  const float* fw = (const float*)d_in[4];
  const float* fb = (const float*)d_in[5];
  const float* pw = (const float*)d_in[6];
  const float* pb = (const float*)d_in[7];
  float* out = (float*)d_out;
  float* ws  = (float*)d_ws;   // needs 24848 floats ~ 100 KB

  pre_kernel<<<73, 512, 0, stream>>>(Wq, Wk, Wv, pw, ws);
  main_kernel<<<16*128, 256, 0, stream>>>(x, fw, fb, pb, ws, out);
}

// Round 21
// 45.721 us; speedup vs baseline: 1.2132x; 1.0168x over previous
//
#include <hip/hip_runtime.h>
#include <hip/hip_bf16.h>

// B=16, C=64, P=128, L=16, D=256, NPF=256, NRFF=128, FEAT=656
// ws layout (float slots):
#define WS_WK0   0        // 16     wk0 = Wk0^T q0
#define WS_A     16       // 256    A = Wq1^T Wk1
#define WS_E0    272      // 4096   E0 = Pp0 * Wv0  (256 x 16), f32 (for c0)
#define WS_BT    4368     // 20480 f32-slots = 40960 ushort: BTall[256][160] bf16
//   BTall[d][kk]: 0..15 Px; 16..31 E1; 32..95 Psin; 96..159 Pcos

typedef float f32x4 __attribute__((ext_vector_type(4)));
typedef short s16x8 __attribute__((ext_vector_type(8)));
typedef short s16x4 __attribute__((ext_vector_type(4)));

static __device__ __forceinline__ short bf16b(float f) {
  __hip_bfloat16 h = __float2bfloat16(f);
  return __builtin_bit_cast(short, h);
}
static __device__ __forceinline__ float bf2f(short s) {
  unsigned u = ((unsigned)(unsigned short)s) << 16;
  return __builtin_bit_cast(float, u);
}

// lgkmcnt-only barrier: orders LDS producer->consumer without draining vmcnt.
static __device__ __forceinline__ void bar_lds() {
  asm volatile("s_waitcnt lgkmcnt(0)\n\ts_barrier" ::: "memory");
}

// Pre v3: 138 blocks. Block 0 = A only; block 137 = q0+wk0 (was serially
// chained inside block 0); E0/E1 = 4 d's/block over 128 blocks; RFF = 8 blocks.
__global__ __launch_bounds__(512)
void pre_kernel(const float* __restrict__ Wq, const float* __restrict__ Wk,
                const float* __restrict__ Wv, const float* __restrict__ pw,
                float* __restrict__ ws)
{
  __shared__ float lds[8192];
  const int t = threadIdx.x;
  const int blk = blockIdx.x;
  ushort* bt = (ushort*)(ws + WS_BT);

  if (blk == 0) {
    // ---- A = Wq1^T * Wk1 ----
    {
      const int d = t >> 1;
      const int lb = (t & 1) * 8;
      #pragma unroll
      for (int h = 0; h < 2; ++h) {
        const float4 vq = *(const float4*)(Wq + 4096 + t*8 + h*4);
        lds[(lb+h*4+0)*256 + d] = vq.x;
        lds[(lb+h*4+1)*256 + d] = vq.y;
        lds[(lb+h*4+2)*256 + d] = vq.z;
        lds[(lb+h*4+3)*256 + d] = vq.w;
        const float4 vk = *(const float4*)(Wk + 4096 + t*8 + h*4);
        lds[4096 + (lb+h*4+0)*256 + d] = vk.x;
        lds[4096 + (lb+h*4+1)*256 + d] = vk.y;
        lds[4096 + (lb+h*4+2)*256 + d] = vk.z;
        lds[4096 + (lb+h*4+3)*256 + d] = vk.w;
      }
    }
    __syncthreads();
    if (t < 256) {
      const int l1 = t >> 4, l2 = t & 15;
      const float* r1 = lds + l1*256;
      const float* r2 = lds + 4096 + l2*256;
      float s = 0.f;
      #pragma unroll 8
      for (int dq = 0; dq < 64; ++dq) {
        const float4 a = *(const float4*)(r1 + dq*4);
        const float4 b = *(const float4*)(r2 + dq*4);
        s += a.x*b.x + a.y*b.y + a.z*b.z + a.w*b.w;    // A[l1,l2]
      }
      ws[WS_A + t] = s;
    }
  } else if (blk == 137) {
    // ---- q0 + wk0 = Wk0^T q0 ----
    if (t < 256) {
      float s = 0.f;
      #pragma unroll
      for (int q = 0; q < 4; ++q) {
        const float4 v = *(const float4*)(Wq + t*16 + q*4);
        s += v.x + v.y + v.z + v.w;           // q0[d]
      }
      lds[t] = s;
    }
    __syncthreads();
    if (t < 256) {                 // wk0 partial sums over d-chunks
      const int l = t & 15, ch = t >> 4;
      float s = 0.f;
      #pragma unroll
      for (int i = 0; i < 16; ++i)
        s += lds[ch*16 + i] * Wk[(ch*16 + i)*16 + l];
      lds[256 + t] = s;
    }
    __syncthreads();
    if (t < 16) {
      float s = 0.f;
      #pragma unroll
      for (int ch = 0; ch < 16; ++ch) s += lds[256 + ch*16 + t];
      ws[WS_WK0 + t] = s;          // wk0[l]
    }
  } else if (blk <= 128) {
    // E0 (blk 1..64) / E1 (blk 65..128): 4 d's per block
    const int deg = (blk <= 64) ? 0 : 1;
    {
      const int f = t >> 1;
      const int lb = (t & 1) * 8;
      #pragma unroll
      for (int h = 0; h < 2; ++h) {
        const float4 v = *(const float4*)(Wv + deg*4096 + t*8 + h*4);
        lds[(lb+h*4+0)*256 + f] = v.x;
        lds[(lb+h*4+1)*256 + f] = v.y;
        lds[(lb+h*4+2)*256 + f] = v.z;
        lds[(lb+h*4+3)*256 + f] = v.w;
      }
    }
    __syncthreads();
    if (t < 64) {
      const int d = (deg ? (blk-65) : (blk-1))*4 + (t >> 4);
      const int l = t & 15;
      const float* pr = pw + d*656 + (deg ? 272 : 16);
      const float* wv = lds + l*256;
      float s = 0.f;
      #pragma unroll 8
      for (int fq = 0; fq < 64; ++fq) {
        const float4 a = *(const float4*)(pr + fq*4);
        const float4 b = *(const float4*)(wv + fq*4);
        s += a.x*b.x + a.y*b.y + a.z*b.z + a.w*b.w;
      }
      if (deg == 0) {
        ws[WS_E0 + d*16 + l] = s;
        bt[d*160 + l] = (ushort)bf16b(pw[d*656 + l]);
      } else {
        bt[d*160 + 16 + l] = (ushort)bf16b(s);
      }
    }
  } else {
    // RFF projection weights: blk 129..136, 32 d's each (coalesced along j)
    const int idx = blk - 129;
    #pragma unroll
    for (int k = 0; k < 8; ++k) {
      const int d = idx*32 + k*4 + (t >> 7);
      const int j = t & 127;
      const float v = (j < 64) ? pw[d*656 + 528 + j] : pw[d*656 + 592 + (j-64)];
      bt[d*160 + 32 + j] = (ushort)bf16b(v);
    }
  }
}

__global__ __launch_bounds__(256, 2)
void main_kernel(const float* __restrict__ x, const float* __restrict__ fw,
                 const float* __restrict__ fb, const float* __restrict__ pb,
                 const float* __restrict__ ws, float* __restrict__ out)
{
  __shared__ short Xb[64*40];    // bf16 X [c][k], 80B rows; k in [16,32) zero
  __shared__ short XbT[16*72];   // bf16 X^T [l][c], 144B rows
  __shared__ short Fwt[64*40];   // bf16 fw^T [j][k]; k>=16 zero
  __shared__ float fbs[64];
  __shared__ float Gs[256];      // G = X^T X (f32, from MFMA)
  __shared__ float AGs[256];     // AG = A * G
  __shared__ float tls[16];      // G * wk0
  __shared__ float c0s[256];     // pb + E0 * tls
  __shared__ __align__(16) short Abf[20*64*8];
  // bf16 acts [kt][c][8]: kt0-1=x, kt2-3=M, kt4-11=sin, kt12-19=cos
  // after P5 reused as f32 tile [16][260] for the contiguous-store transpose
  // ~36.6 KB

  const int t = threadIdx.x;
  const int b = blockIdx.x >> 7;
  const int p = blockIdx.x & 127;

  const int lane = t & 63, w = t >> 6;
  const int n0 = w << 6;                    // wave's d-offset
  const int lr = lane & 15, lq = lane >> 4;
  const int xc = t >> 2, xl0 = (t & 3) * 4;
  const ushort* BTW = (const ushort*)(ws + WS_BT);

  // ---- P1: stage X (3 bf16 layouts) + fw^T + fb ----
  {
    const float4 v = *(const float4*)(x + (((b*64 + xc)*128 + p) << 4) + xl0);
    s16x4 xb;
    xb[0] = bf16b(v.x); xb[1] = bf16b(v.y); xb[2] = bf16b(v.z); xb[3] = bf16b(v.w);
    s16x4 z; z[0] = 0; z[1] = 0; z[2] = 0; z[3] = 0;
    *(s16x4*)&Xb[xc*40 + xl0] = xb;
    *(s16x4*)&Xb[xc*40 + 16 + xl0] = z;            // zero-pad k 16..31
    XbT[(xl0+0)*72 + xc] = xb[0];
    XbT[(xl0+1)*72 + xc] = xb[1];
    XbT[(xl0+2)*72 + xc] = xb[2];
    XbT[(xl0+3)*72 + xc] = xb[3];
    *(s16x4*)&Abf[(((xl0>>3)*64 + xc) << 3) + (xl0 & 4)] = xb;
    // fw^T: thread covers fw row l = t>>4, cols j0..j0+3
    const int l = t >> 4, j0 = (t & 15) * 4;
    const float4 f = *(const float4*)(fw + l*64 + j0);
    Fwt[(j0+0)*40 + l] = (short)bf16b(f.x);
    Fwt[(j0+1)*40 + l] = (short)bf16b(f.y);
    Fwt[(j0+2)*40 + l] = (short)bf16b(f.z);
    Fwt[(j0+3)*40 + l] = (short)bf16b(f.w);
    *(s16x4*)&Fwt[(t>>2)*40 + 16 + (t & 3)*4] = z; // zero-pad k 16..31
    if (t < 16) *(float4*)(fbs + t*4) = *(const float4*)(fb + t*4);
  }
  bar_lds();  // B1

  // ---- P2a (wave 0): G = X^T X via MFMA, A = B = XbT fragment ----
  if (w == 0) {
    f32x4 g = {};
    #pragma unroll
    for (int ks = 0; ks < 2; ++ks) {
      const s16x8 xa = *(const s16x8*)&XbT[lr*72 + ks*32 + lq*8];
      g = __builtin_amdgcn_mfma_f32_16x16x32_bf16(xa, xa, g, 0, 0, 0);
    }
    #pragma unroll
    for (int r = 0; r < 4; ++r) Gs[(lq*4 + r)*16 + lr] = g[r];
  }
  // ---- P2b (all waves): wx = X*fw via MFMA; j-block = w; sincos -> Abf ----
  {
    s16x8 xa[4];
    #pragma unroll
    for (int mi = 0; mi < 4; ++mi)
      xa[mi] = *(const s16x8*)&Xb[(mi*16 + lr)*40 + lq*8];
    const s16x8 fwf = *(const s16x8*)&Fwt[(w*16 + lr)*40 + lq*8];
    f32x4 wa[4];
    #pragma unroll
    for (int mi = 0; mi < 4; ++mi) {
      f32x4 zz = {};
      wa[mi] = __builtin_amdgcn_mfma_f32_16x16x32_bf16(xa[mi], fwf, zz, 0, 0, 0);
    }
    const float fbj = fbs[w*16 + lr];          // lane's j = w*16 + lr
    const int ktS = 4 + 2*w + (lr >> 3);       // sin row: 4 + j/8
    const int ktC = ktS + 8;                   // cos row
    const int e = lr & 7;                      // j % 8
    #pragma unroll
    for (int mi = 0; mi < 4; ++mi) {
      #pragma unroll
      for (int r = 0; r < 4; ++r) {
        const int c = mi*16 + lq*4 + r;        // D row = c
        float sv, cv;
        __sincosf(wa[mi][r] + fbj, &sv, &cv);
        Abf[(ktS*64 + c)*8 + e] = bf16b(sv);
        Abf[(ktC*64 + c)*8 + e] = bf16b(cv);
      }
    }
  }
  bar_lds();  // B2

  // ---- P3: AG = A*G ; tls = G*wk0 ----
  {
    const int l = t >> 4, lp = t & 15;
    float a[16];
    #pragma unroll
    for (int q = 0; q < 4; ++q)
      *(float4*)(a + q*4) = *(const float4*)(ws + WS_A + l*16 + q*4);
    float s = 0.f;
    #pragma unroll
    for (int k = 0; k < 16; ++k) s += a[k] * Gs[k*16 + lp];
    AGs[t] = s;
  }
  if (t < 16) {
    float s = 0.f;
    #pragma unroll
    for (int q = 0; q < 4; ++q) {
      const float4 g = *(const float4*)(Gs + t*16 + q*4);
      const float4 wk = *(const float4*)(ws + WS_WK0 + q*4);
      s += g.x*wk.x + g.y*wk.y + g.z*wk.z + g.w*wk.w;
    }
    tls[t] = s;
  }
  bar_lds();  // B3

  // ---- P4: M = X*AG -> Abf kt2-3 ; c0s ----
  {
    const s16x8 xlo = *(const s16x8*)&Xb[xc*40];
    const s16x8 xhi = *(const s16x8*)&Xb[xc*40 + 8];
    float4 m = make_float4(0.f, 0.f, 0.f, 0.f);
    #pragma unroll
    for (int i = 0; i < 8; ++i) {
      const float xv = bf2f(xlo[i]);
      const float4 g = *(const float4*)(AGs + i*16 + xl0);
      m.x += xv*g.x; m.y += xv*g.y; m.z += xv*g.z; m.w += xv*g.w;
    }
    #pragma unroll
    for (int i = 0; i < 8; ++i) {
      const float xv = bf2f(xhi[i]);
      const float4 g = *(const float4*)(AGs + (8+i)*16 + xl0);
      m.x += xv*g.x; m.y += xv*g.y; m.z += xv*g.z; m.w += xv*g.w;
    }
    s16x4 mb;
    mb[0] = bf16b(m.x); mb[1] = bf16b(m.y); mb[2] = bf16b(m.z); mb[3] = bf16b(m.w);
    *(s16x4*)&Abf[(((2 + (xl0>>3))*64 + xc) << 3) + (xl0 & 4)] = mb;
  }
  {
    float tl[16], e[16];
    #pragma unroll
    for (int q = 0; q < 4; ++q) {
      *(float4*)(tl + q*4) = *(const float4*)(tls + q*4);
      *(float4*)(e + q*4) = *(const float4*)(ws + WS_E0 + t*16 + q*4);
    }
    float s = pb[t];
    #pragma unroll
    for (int l = 0; l < 16; ++l) s += tl[l] * e[l];
    c0s[t] = s;
  }
  bar_lds();  // B4

  // ---- P5: MFMA, A = acts (rows c), B = weights (cols d); K = 160 ----
  f32x4 acc[4][4] = {};                  // [mi: c-tile][nt: d-tile]
  #pragma unroll
  for (int ks = 0; ks < 5; ++ks) {
    s16x8 af[4], bf_[4];
    #pragma unroll
    for (int mi = 0; mi < 4; ++mi)
      af[mi] = *(const s16x8*)&Abf[(((ks*4 + lq)*64) + mi*16 + lr) << 3];
    #pragma unroll
    for (int nt = 0; nt < 4; ++nt)
      bf_[nt] = *(const s16x8*)&BTW[(n0 + nt*16 + lr)*160 + ks*32 + lq*8];
    #pragma unroll
    for (int mi = 0; mi < 4; ++mi)
      #pragma unroll
      for (int nt = 0; nt < 4; ++nt)
        acc[mi][nt] = __builtin_amdgcn_mfma_f32_16x16x32_bf16(af[mi], bf_[nt], acc[mi][nt], 0, 0, 0);
  }

  // ---- epilogue: transpose via LDS (reuse Abf) -> fully-contiguous stores ----
  bar_lds();  // all waves finished reading Abf in P5
  float* tile = (float*)Abf;   // [16][260] f32, pad 260 -> benign 2-way bank alias
  #pragma unroll
  for (int mi = 0; mi < 4; ++mi) {
    #pragma unroll
    for (int nt = 0; nt < 4; ++nt) {
      const int d = n0 + nt*16 + lr;
      const float cc = c0s[d];
      #pragma unroll
      for (int r = 0; r < 4; ++r)
        tile[(lq*4 + r)*260 + d] = acc[mi][nt][r] + cc;
    }
    bar_lds();
    #pragma unroll
    for (int round = 0; round < 4; ++round) {
      const int cr = round*4 + w;
      const int c = mi*16 + cr;
      const float4 v = *(const float4*)&tile[cr*260 + lane*4];
      *(float4*)(out + (((b*64 + c)*128 + p) << 8) + lane*4) = v;
    }
    bar_lds();  // reads done before next mi overwrites tile
  }
}

extern "C" void kernel_launch(void* const* d_in, const int* in_sizes, int n_in,
                              void* d_out, int out_size, void* d_ws, size_t ws_size,
                              hipStream_t stream) {
  const float* x  = (const float*)d_in[0];
  const float* Wq = (const float*)d_in[1];
  const float* Wk = (const float*)d_in[2];
  const float* Wv = (const float*)d_in[3];
  const float* fw = (const float*)d_in[4];
  const float* fb = (const float*)d_in[5];
  const float* pw = (const float*)d_in[6];
  const float* pb = (const float*)d_in[7];
  float* out = (float*)d_out;
  float* ws  = (float*)d_ws;   // needs 24848 floats ~ 100 KB

  pre_kernel<<<138, 512, 0, stream>>>(Wq, Wk, Wv, pw, ws);
  main_kernel<<<16*128, 256, 0, stream>>>(x, fw, fb, pb, ws, out);
}